// Round 1
// baseline (449.246 us; speedup 1.0000x reference)
//
#include <hip/hip_runtime.h>

// CoarseMatching dual-softmax on MI355X.
// N=2, L=S=4800, C=256. sim = f0.f1^T/(256*0.1); conf = softmax_l * softmax_s.
// GEMM path: bf16 hi/lo split -> K=768 bf16 MFMA GEMM (hi*hi + hi*lo + lo*hi).
// sim is materialized in d_out's conf region and overwritten in place by conf.

#define Ncst 2
#define Lc 4800
#define Sc 4800
#define Cc 256
#define K3 768          // 3*C expanded K
#define LP 4864         // 4800 padded to 38*128
#define THRC 0.2f

typedef float f32x4 __attribute__((ext_vector_type(4)));
typedef __bf16 bf16x8 __attribute__((ext_vector_type(8)));

#define AS1(p) ((__attribute__((address_space(1))) void*)(p))
#define AS3(p) ((__attribute__((address_space(3))) void*)(p))

__device__ inline unsigned short f2bf(float x) {
    unsigned u = __float_as_uint(x);
    unsigned r = (u + 0x7fffu + ((u >> 16) & 1u)) >> 16;
    return (unsigned short)r;
}
__device__ inline float bf2f(unsigned short h) {
    return __uint_as_float(((unsigned)h) << 16);
}

// ---------------- conversion: build A3 [N][LP][768], B3 [N][LP][768] bf16 ----
// A3 segments: [a_hi | a_hi | a_lo]; B3 segments: [b_hi | b_lo | b_hi]
// => dot over 768 = hi.hi + hi.lo + lo.hi
__global__ __launch_bounds__(256) void convert_kernel(
    const float* __restrict__ f0, const float* __restrict__ f1,
    unsigned short* __restrict__ A3, unsigned short* __restrict__ B3)
{
    int idx = blockIdx.x * 256 + threadIdx.x;      // over N*LP*C
    if (idx >= Ncst * LP * Cc) return;
    int k   = idx & (Cc - 1);
    int row = (idx >> 8) % LP;
    int n   = idx / (LP * Cc);
    size_t base = ((size_t)n * LP + row) * K3;

    float a = 0.f;
    if (row < Lc) a = f0[((size_t)n * Lc + row) * Cc + k];
    unsigned short ahi = f2bf(a);
    unsigned short alo = f2bf(a - bf2f(ahi));
    A3[base + k]       = ahi;
    A3[base + 256 + k] = ahi;
    A3[base + 512 + k] = alo;

    float b = 0.f;
    if (row < Sc) b = f1[((size_t)n * Sc + row) * Cc + k];
    unsigned short bhi = f2bf(b);
    unsigned short blo = f2bf(b - bf2f(bhi));
    B3[base + k]       = bhi;
    B3[base + 256 + k] = blo;
    B3[base + 512 + k] = bhi;
}

// ---------------- GEMM: sim[n][l][s] = A3[n][l][:] . B3[n][s][:] * 5/128 -----
// 128x128 tile, 4 waves (2x2), each wave 64x64 via 4x4 grid of 16x16x32 MFMAs.
__global__ __launch_bounds__(256) void gemm_kernel(
    const unsigned short* __restrict__ A3, const unsigned short* __restrict__ B3,
    float* __restrict__ simout)
{
    __shared__ unsigned short lA[128 * 32];   // 8 KB, row-major [row][k]
    __shared__ unsigned short lB[128 * 32];

    const int n    = blockIdx.z;
    const int tm   = blockIdx.y;
    const int tn   = blockIdx.x;
    const int tid  = threadIdx.x;
    const int wave = tid >> 6;
    const int lane = tid & 63;
    const int wm   = wave >> 1;     // 0..1
    const int wn   = wave & 1;      // 0..1
    const int ml   = lane & 15;
    const int kq   = lane >> 4;     // 0..3

    const unsigned short* Ab = A3 + ((size_t)n * LP + (size_t)tm * 128) * K3;
    const unsigned short* Bb = B3 + ((size_t)n * LP + (size_t)tn * 128) * K3;

    f32x4 acc[4][4] = {};

    for (int k0 = 0; k0 < K3; k0 += 32) {
        __syncthreads();
        // stage 8KB per tile = 8 chunks of 1KB (64 lanes x 16B); wave handles 2 chunks each
#pragma unroll
        for (int cc = 0; cc < 2; ++cc) {
            int c    = wave * 2 + cc;            // 0..7
            int eoff = c * 512 + lane * 8;       // element offset in tile
            int row  = eoff >> 5;
            int kcol = eoff & 31;
            const unsigned short* ga = Ab + (size_t)row * K3 + (k0 + kcol);
            const unsigned short* gb = Bb + (size_t)row * K3 + (k0 + kcol);
            __builtin_amdgcn_global_load_lds(AS1(ga), AS3(lA + c * 512), 16, 0, 0);
            __builtin_amdgcn_global_load_lds(AS1(gb), AS3(lB + c * 512), 16, 0, 0);
        }
        __syncthreads();

        bf16x8 af[4], bf[4];
#pragma unroll
        for (int i = 0; i < 4; ++i) {
            int arow = wm * 64 + i * 16 + ml;
            af[i] = *(const bf16x8*)&lA[arow * 32 + kq * 8];
            int brow = wn * 64 + i * 16 + ml;
            bf[i] = *(const bf16x8*)&lB[brow * 32 + kq * 8];
        }
#pragma unroll
        for (int i = 0; i < 4; ++i)
#pragma unroll
            for (int j = 0; j < 4; ++j)
                acc[i][j] = __builtin_amdgcn_mfma_f32_16x16x32_bf16(af[i], bf[j], acc[i][j], 0, 0, 0);
    }

    // epilogue: D[row][col]: col = lane&15, row = (lane>>4)*4 + r
    const float alpha = 5.0f / 128.0f;          // 1/(256*0.1), exact in fp32
#pragma unroll
    for (int i = 0; i < 4; ++i) {
#pragma unroll
        for (int j = 0; j < 4; ++j) {
#pragma unroll
            for (int r = 0; r < 4; ++r) {
                int gl = tm * 128 + wm * 64 + i * 16 + kq * 4 + r;
                int gs = tn * 128 + wn * 64 + j * 16 + ml;
                if (gl < Lc && gs < Sc)
                    simout[((size_t)n * Lc + gl) * Sc + gs] = acc[i][j][r] * alpha;
            }
        }
    }
}

// ---------------- row stats: max + sum(exp) over s for each (n,l) ------------
__global__ __launch_bounds__(256) void row_stats_kernel(
    const float* __restrict__ sim, float* __restrict__ rm, float* __restrict__ rsinv)
{
    __shared__ float shm[256], shs[256];
    int b = blockIdx.x;                          // n*Lc + l
    const float* row = sim + (size_t)b * Sc;
    int tid = threadIdx.x;
    float m = -3.0e38f, s = 0.f;
    for (int j = tid; j < Sc; j += 256) {
        float x = row[j];
        if (x > m) { s = s * __expf(m - x) + 1.f; m = x; }
        else       { s += __expf(x - m); }
    }
    shm[tid] = m; shs[tid] = s;
    __syncthreads();
    for (int off = 128; off; off >>= 1) {
        if (tid < off) {
            float m1 = shm[tid], s1 = shs[tid];
            float m2 = shm[tid + off], s2 = shs[tid + off];
            float M = fmaxf(m1, m2);
            shm[tid] = M;
            shs[tid] = s1 * __expf(m1 - M) + s2 * __expf(m2 - M);
        }
        __syncthreads();
    }
    if (tid == 0) { rm[b] = shm[0]; rsinv[b] = 1.f / shs[0]; }
}

// ---------------- col stats: partials over l-chunks, coalesced in s ----------
#define LCH 32
#define LCHUNK (Lc / LCH)   // 150
__global__ __launch_bounds__(256) void col_part_kernel(
    const float* __restrict__ sim, float* __restrict__ pm, float* __restrict__ ps)
{
    int s  = blockIdx.x * 256 + threadIdx.x;
    int ch = blockIdx.y;
    int n  = blockIdx.z;
    if (s >= Sc) return;
    const float* base = sim + (size_t)n * Lc * Sc + (size_t)ch * LCHUNK * Sc + s;
    float m = -3.0e38f, acc = 0.f;
    for (int l = 0; l < LCHUNK; ++l) {
        float x = base[(size_t)l * Sc];
        if (x > m) { acc = acc * __expf(m - x) + 1.f; m = x; }
        else       { acc += __expf(x - m); }
    }
    size_t o = ((size_t)ch * Ncst + n) * Sc + s;
    pm[o] = m; ps[o] = acc;
}

__global__ __launch_bounds__(256) void col_merge_kernel(
    const float* __restrict__ pm, const float* __restrict__ ps,
    float* __restrict__ cm, float* __restrict__ csinv)
{
    int i = blockIdx.x * 256 + threadIdx.x;      // n*Sc + s
    if (i >= Ncst * Sc) return;
    int n = i / Sc, s = i % Sc;
    float M = -3.0e38f;
    for (int c = 0; c < LCH; ++c)
        M = fmaxf(M, pm[((size_t)c * Ncst + n) * Sc + s]);
    float S = 0.f;
    for (int c = 0; c < LCH; ++c) {
        size_t o = ((size_t)c * Ncst + n) * Sc + s;
        S += ps[o] * __expf(pm[o] - M);
    }
    cm[i] = M; csinv[i] = 1.f / S;
}

// ---------------- conf: in-place sim -> conf; track per-row conf max ---------
__global__ __launch_bounds__(256) void conf_kernel(
    float* __restrict__ confio,
    const float* __restrict__ rm, const float* __restrict__ rsinv,
    const float* __restrict__ cm, const float* __restrict__ csinv,
    float* __restrict__ rcm)
{
    __shared__ float sh[256];
    int b = blockIdx.x;                          // n*Lc + l
    int n = b / Lc;
    float* row = confio + (size_t)b * Sc;
    const float* cmn = cm + (size_t)n * Sc;
    const float* cin = csinv + (size_t)n * Sc;
    int tid = threadIdx.x;
    float rmv = rm[b], riv = rsinv[b];
    float lmax = 0.f;
    for (int s = tid; s < Sc; s += 256) {
        float x = row[s];
        float c = __expf(2.f * x - rmv - cmn[s]) * riv * cin[s];
        row[s] = c;
        lmax = fmaxf(lmax, c);
    }
    sh[tid] = lmax;
    __syncthreads();
    for (int off = 128; off; off >>= 1) {
        if (tid < off) sh[tid] = fmaxf(sh[tid], sh[tid + off]);
        __syncthreads();
    }
    if (tid == 0) rcm[b] = sh[0];
}

// ---------------- finalize: threshold + border + mutual-NN -------------------
// Gated by rowmax_conf > THR (any mask-true entry must equal rowmax > THR),
// so the O(S*L) scan only runs for candidate rows (none with this data).
__global__ __launch_bounds__(256) void finalize_kernel(
    const float* __restrict__ conf, const float* __restrict__ rcm,
    const int* __restrict__ h0p, const int* __restrict__ w0p,
    const int* __restrict__ h1p, const int* __restrict__ w1p,
    float* __restrict__ out_match, float* __restrict__ out_j, float* __restrict__ out_mconf)
{
    int i = blockIdx.x * 256 + threadIdx.x;      // n*Lc + l
    if (i >= Ncst * Lc) return;
    int n = i / Lc, l = i % Lc;
    float mm = rcm[i];
    float fm = 0.f, fj = 0.f, fc = 0.f;
    if (mm > THRC) {
        int w0 = *w0p, w1 = *w1p;
        if ((l / w0) >= 2 && (l % w0) >= 2) {
            const float* rowp = conf + ((size_t)n * Lc + l) * Sc;
            for (int s = 0; s < Sc; ++s) {
                float c = rowp[s];
                if (c == mm && (s / w1) >= 2 && (s % w1) >= 2) {
                    bool ismax = true;
                    const float* colp = conf + (size_t)n * Lc * Sc + s;
                    for (int lp = 0; lp < Lc; ++lp) {
                        if (colp[(size_t)lp * Sc] > c) { ismax = false; break; }
                    }
                    if (ismax) { fm = 1.f; fj = (float)s; fc = c; break; }
                }
            }
        }
    }
    out_match[i] = fm; out_j[i] = fj; out_mconf[i] = fc;
}

extern "C" void kernel_launch(void* const* d_in, const int* in_sizes, int n_in,
                              void* d_out, int out_size, void* d_ws, size_t ws_size,
                              hipStream_t stream) {
    const float* f0 = (const float*)d_in[0];
    const float* f1 = (const float*)d_in[1];
    const int* h0p = (const int*)d_in[2];
    const int* w0p = (const int*)d_in[3];
    const int* h1p = (const int*)d_in[4];
    const int* w1p = (const int*)d_in[5];

    // workspace layout (bytes); total ~32.5 MB
    char* ws = (char*)d_ws;
    unsigned short* A3 = (unsigned short*)ws;                  // 14,942,208 B
    unsigned short* B3 = (unsigned short*)(ws + 14942208);     // 14,942,208 B
    float* rm    = (float*)(ws + 29884416);                    // 38,400 B
    float* rsinv = (float*)(ws + 29922816);
    float* cm    = (float*)(ws + 29961216);
    float* csinv = (float*)(ws + 29999616);
    float* rcm   = (float*)(ws + 30038016);
    float* pm    = (float*)(ws + 30076416);                    // 1,228,800 B
    float* ps    = (float*)(ws + 31305216);                    // 1,228,800 B

    float* conf      = (float*)d_out;                          // [N][L][S], holds sim then conf
    float* out_match = conf + (size_t)Ncst * Lc * Sc;
    float* out_j     = out_match + Ncst * Lc;
    float* out_mconf = out_j + Ncst * Lc;

    convert_kernel<<<(Ncst * LP * Cc + 255) / 256, 256, 0, stream>>>(f0, f1, A3, B3);

    dim3 gg(LP / 128, LP / 128, Ncst);   // 38 x 38 x 2
    gemm_kernel<<<gg, 256, 0, stream>>>(A3, B3, conf);

    row_stats_kernel<<<Ncst * Lc, 256, 0, stream>>>(conf, rm, rsinv);

    dim3 cg((Sc + 255) / 256, LCH, Ncst);   // 19 x 32 x 2
    col_part_kernel<<<cg, 256, 0, stream>>>(conf, pm, ps);
    col_merge_kernel<<<(Ncst * Sc + 255) / 256, 256, 0, stream>>>(pm, ps, cm, csinv);

    conf_kernel<<<Ncst * Lc, 256, 0, stream>>>(conf, rm, rsinv, cm, csinv, rcm);

    finalize_kernel<<<(Ncst * Lc + 255) / 256, 256, 0, stream>>>(
        conf, rcm, h0p, w0p, h1p, w1p, out_match, out_j, out_mconf);
}

// Round 2
// 359.502 us; speedup vs baseline: 1.2496x; 1.2496x over previous
//
#include <hip/hip_runtime.h>

// CoarseMatching dual-softmax on MI355X — round 2.
// N=2, L=S=4800, C=256. sim = f0.f1^T/(256*0.1); conf = softmax_l * softmax_s.
// GEMM: bf16 hi/lo split -> K=768 bf16 MFMA GEMM. Fused epilogue computes
// e = exp(sim) (no max-subtraction: |sim| <~ 3), writes e, and atomically
// accumulates row sums rs = sum_s e and col sums cs = sum_l e.
// conf pass: conf = e^2 * (1/rs) * (1/cs), in place in d_out.

#define Ncst 2
#define Lc 4800
#define Sc 4800
#define Cc 256
#define K3 768          // 3*C expanded K
#define LP 4864         // 4800 padded to 38*128
#define THRC 0.2f

typedef float f32x4 __attribute__((ext_vector_type(4)));
typedef __bf16 bf16x8 __attribute__((ext_vector_type(8)));

#define AS1(p) ((__attribute__((address_space(1))) void*)(p))
#define AS3(p) ((__attribute__((address_space(3))) void*)(p))

__device__ inline unsigned short f2bf(float x) {
    unsigned u = __float_as_uint(x);
    unsigned r = (u + 0x7fffu + ((u >> 16) & 1u)) >> 16;
    return (unsigned short)r;
}
__device__ inline float bf2f(unsigned short h) {
    return __uint_as_float(((unsigned)h) << 16);
}

// ---------------- init: zero the atomic sum accumulators ---------------------
__global__ __launch_bounds__(256) void init_kernel(float* __restrict__ rs, float* __restrict__ cs)
{
    int i = blockIdx.x * 256 + threadIdx.x;
    if (i < Ncst * Lc) { rs[i] = 0.f; cs[i] = 0.f; }
}

// ---------------- conversion: A3 [N][LP][768], B3 [N][LP][768] bf16 ----------
// A3 segments: [a_hi | a_hi | a_lo]; B3: [b_hi | b_lo | b_hi]
// => dot over 768 = hi.hi + hi.lo + lo.hi.  Vectorized: 8 k per thread.
__global__ __launch_bounds__(256) void convert_kernel(
    const float* __restrict__ f0, const float* __restrict__ f1,
    unsigned short* __restrict__ A3, unsigned short* __restrict__ B3)
{
    int idx = blockIdx.x * 256 + threadIdx.x;      // over N*LP*(C/8)
    if (idx >= Ncst * LP * (Cc / 8)) return;
    int k8  = idx & (Cc / 8 - 1);                  // 0..31
    int row = (idx >> 5) % LP;
    int n   = idx / (LP * (Cc / 8));
    size_t base = ((size_t)n * LP + row) * K3 + k8 * 8;

    float av[8], bv[8];
    if (row < Lc) {
        const float4* pa = (const float4*)(f0 + ((size_t)n * Lc + row) * Cc + k8 * 8);
        float4 a0 = pa[0], a1 = pa[1];
        av[0]=a0.x; av[1]=a0.y; av[2]=a0.z; av[3]=a0.w;
        av[4]=a1.x; av[5]=a1.y; av[6]=a1.z; av[7]=a1.w;
        const float4* pb = (const float4*)(f1 + ((size_t)n * Sc + row) * Cc + k8 * 8);
        float4 b0 = pb[0], b1 = pb[1];
        bv[0]=b0.x; bv[1]=b0.y; bv[2]=b0.z; bv[3]=b0.w;
        bv[4]=b1.x; bv[5]=b1.y; bv[6]=b1.z; bv[7]=b1.w;
    } else {
        for (int i = 0; i < 8; ++i) { av[i] = 0.f; bv[i] = 0.f; }
    }

    unsigned short ahi[8], alo[8], bhi[8], blo[8];
#pragma unroll
    for (int i = 0; i < 8; ++i) {
        ahi[i] = f2bf(av[i]); alo[i] = f2bf(av[i] - bf2f(ahi[i]));
        bhi[i] = f2bf(bv[i]); blo[i] = f2bf(bv[i] - bf2f(bhi[i]));
    }
    *(uint4*)&A3[base]       = *(uint4*)ahi;
    *(uint4*)&A3[base + 256] = *(uint4*)ahi;
    *(uint4*)&A3[base + 512] = *(uint4*)alo;
    *(uint4*)&B3[base]       = *(uint4*)bhi;
    *(uint4*)&B3[base + 256] = *(uint4*)blo;
    *(uint4*)&B3[base + 512] = *(uint4*)bhi;
}

// ---------------- GEMM + fused exp + row/col sum accumulation ----------------
// 128x128 tile, 4 waves (2x2), each wave 64x64 via 4x4 grid of 16x16x32 MFMAs.
// LDS layout uses a 16B-slot XOR swizzle: slot(row,q) = row*4 + (q ^ ((row>>1)&3))
// -> fragment ds_read_b128 is 2-way-per-bank-group (free) instead of 8-way.
__global__ __launch_bounds__(256) void gemm_kernel(
    const unsigned short* __restrict__ A3, const unsigned short* __restrict__ B3,
    float* __restrict__ eout, float* __restrict__ rs, float* __restrict__ cs)
{
    __shared__ unsigned short lA[128 * 32];   // 8 KB, 512 slots of 8 elements
    __shared__ unsigned short lB[128 * 32];

    const int n    = blockIdx.z;
    const int tm   = blockIdx.y;
    const int tn   = blockIdx.x;
    const int tid  = threadIdx.x;
    const int wave = tid >> 6;
    const int lane = tid & 63;
    const int wm   = wave >> 1;     // 0..1
    const int wn   = wave & 1;      // 0..1
    const int ml   = lane & 15;
    const int kq   = lane >> 4;     // 0..3

    const unsigned short* Ab = A3 + ((size_t)n * LP + (size_t)tm * 128) * K3;
    const unsigned short* Bb = B3 + ((size_t)n * LP + (size_t)tn * 128) * K3;

    f32x4 acc[4][4] = {};

    for (int k0 = 0; k0 < K3; k0 += 32) {
        __syncthreads();
        // stage 8KB per matrix: 512 slots of 16B; slot s holds (row=s>>2, q=(s&3)^((row>>1)&3))
#pragma unroll
        for (int cc = 0; cc < 2; ++cc) {
            int c    = wave * 2 + cc;            // 0..7
            int slot = c * 64 + lane;            // 0..511
            int row  = slot >> 2;
            int q    = (slot & 3) ^ ((row >> 1) & 3);
            const unsigned short* ga = Ab + (size_t)row * K3 + (k0 + q * 8);
            const unsigned short* gb = Bb + (size_t)row * K3 + (k0 + q * 8);
            __builtin_amdgcn_global_load_lds(AS1(ga), AS3(lA + (size_t)slot * 8), 16, 0, 0);
            __builtin_amdgcn_global_load_lds(AS1(gb), AS3(lB + (size_t)slot * 8), 16, 0, 0);
        }
        __syncthreads();

        bf16x8 af[4], bfr[4];
#pragma unroll
        for (int i = 0; i < 4; ++i) {
            int arow = wm * 64 + i * 16 + ml;
            int aslot = arow * 4 + (kq ^ ((arow >> 1) & 3));
            af[i] = *(const bf16x8*)&lA[aslot * 8];
            int brow = wn * 64 + i * 16 + ml;
            int bslot = brow * 4 + (kq ^ ((brow >> 1) & 3));
            bfr[i] = *(const bf16x8*)&lB[bslot * 8];
        }
#pragma unroll
        for (int i = 0; i < 4; ++i)
#pragma unroll
            for (int j = 0; j < 4; ++j)
                acc[i][j] = __builtin_amdgcn_mfma_f32_16x16x32_bf16(af[i], bfr[j], acc[i][j], 0, 0, 0);
    }

    // ---- epilogue: e = exp(alpha*sim); store; accumulate row/col sums ----
    // D[row][col]: col = lane&15, row = (lane>>4)*4 + r
    const float alpha = 5.0f / 128.0f;          // 1/(256*0.1), exact in fp32
#pragma unroll
    for (int i = 0; i < 4; ++i) {
#pragma unroll
        for (int r = 0; r < 4; ++r) {
            int gl = tm * 128 + wm * 64 + i * 16 + kq * 4 + r;
            bool rok = gl < Lc;
#pragma unroll
            for (int j = 0; j < 4; ++j) {
                int gs = tn * 128 + wn * 64 + j * 16 + ml;
                bool ok = rok && (gs < Sc);
                float ev = ok ? __expf(acc[i][j][r] * alpha) : 0.f;
                acc[i][j][r] = ev;
                if (ok) eout[((size_t)n * Lc + gl) * Sc + gs] = ev;
            }
        }
    }
    // row sums: reduce over j and over ml lanes (xor 1,2,4,8 stays in quarter)
#pragma unroll
    for (int i = 0; i < 4; ++i) {
#pragma unroll
        for (int r = 0; r < 4; ++r) {
            float rp = acc[i][0][r] + acc[i][1][r] + acc[i][2][r] + acc[i][3][r];
            rp += __shfl_xor(rp, 1);
            rp += __shfl_xor(rp, 2);
            rp += __shfl_xor(rp, 4);
            rp += __shfl_xor(rp, 8);
            int gl = tm * 128 + wm * 64 + i * 16 + kq * 4 + r;
            if (ml == 0 && gl < Lc) atomicAdd(&rs[(size_t)n * Lc + gl], rp);
        }
    }
    // col sums: reduce over i,r and over kq (xor 16, 32)
#pragma unroll
    for (int j = 0; j < 4; ++j) {
        float cp = 0.f;
#pragma unroll
        for (int i = 0; i < 4; ++i)
#pragma unroll
            for (int r = 0; r < 4; ++r) cp += acc[i][j][r];
        cp += __shfl_xor(cp, 16);
        cp += __shfl_xor(cp, 32);
        int gs = tn * 128 + wn * 64 + j * 16 + ml;
        if (kq == 0 && gs < Sc) atomicAdd(&cs[(size_t)n * Sc + gs], cp);
    }
}

// ---------------- reciprocal of sums ----------------------------------------
__global__ __launch_bounds__(256) void inv_kernel(
    const float* __restrict__ rs, const float* __restrict__ cs,
    float* __restrict__ rsinv, float* __restrict__ csinv)
{
    int i = blockIdx.x * 256 + threadIdx.x;
    if (i < Ncst * Lc) { rsinv[i] = 1.0f / rs[i]; csinv[i] = 1.0f / cs[i]; }
}

// ---------------- conf: in-place e -> conf = e^2*rsinv*csinv; row conf max ---
__global__ __launch_bounds__(256) void conf_kernel(
    float* __restrict__ confio,
    const float* __restrict__ rsinv, const float* __restrict__ csinv,
    float* __restrict__ rcm)
{
    __shared__ float sh[256];
    int b = blockIdx.x;                          // n*Lc + l
    int n = b / Lc;
    f32x4* row = (f32x4*)(confio + (size_t)b * Sc);
    const f32x4* civ = (const f32x4*)(csinv + (size_t)n * Sc);
    int tid = threadIdx.x;
    float riv = rsinv[b];
    float lmax = 0.f;
    for (int v = tid; v < Sc / 4; v += 256) {
        f32x4 e4 = row[v];
        f32x4 c4 = civ[v];
        f32x4 o  = e4 * e4 * riv * c4;
        row[v] = o;
        lmax = fmaxf(lmax, fmaxf(fmaxf(o.x, o.y), fmaxf(o.z, o.w)));
    }
    sh[tid] = lmax;
    __syncthreads();
    for (int off = 128; off; off >>= 1) {
        if (tid < off) sh[tid] = fmaxf(sh[tid], sh[tid + off]);
        __syncthreads();
    }
    if (tid == 0) rcm[b] = sh[0];
}

// ---------------- finalize: threshold + border + mutual-NN -------------------
// Gated by rowmax_conf > THR (any mask-true entry must equal rowmax > THR).
__global__ __launch_bounds__(256) void finalize_kernel(
    const float* __restrict__ conf, const float* __restrict__ rcm,
    const int* __restrict__ h0p, const int* __restrict__ w0p,
    const int* __restrict__ h1p, const int* __restrict__ w1p,
    float* __restrict__ out_match, float* __restrict__ out_j, float* __restrict__ out_mconf)
{
    int i = blockIdx.x * 256 + threadIdx.x;      // n*Lc + l
    if (i >= Ncst * Lc) return;
    int n = i / Lc, l = i % Lc;
    float mm = rcm[i];
    float fm = 0.f, fj = 0.f, fc = 0.f;
    if (mm > THRC) {
        int w0 = *w0p, w1 = *w1p;
        if ((l / w0) >= 2 && (l % w0) >= 2) {
            const float* rowp = conf + ((size_t)n * Lc + l) * Sc;
            for (int s = 0; s < Sc; ++s) {
                float c = rowp[s];
                if (c == mm && (s / w1) >= 2 && (s % w1) >= 2) {
                    bool ismax = true;
                    const float* colp = conf + (size_t)n * Lc * Sc + s;
                    for (int lp = 0; lp < Lc; ++lp) {
                        if (colp[(size_t)lp * Sc] > c) { ismax = false; break; }
                    }
                    if (ismax) { fm = 1.f; fj = (float)s; fc = c; break; }
                }
            }
        }
    }
    out_match[i] = fm; out_j[i] = fj; out_mconf[i] = fc;
}

extern "C" void kernel_launch(void* const* d_in, const int* in_sizes, int n_in,
                              void* d_out, int out_size, void* d_ws, size_t ws_size,
                              hipStream_t stream) {
    const float* f0 = (const float*)d_in[0];
    const float* f1 = (const float*)d_in[1];
    const int* h0p = (const int*)d_in[2];
    const int* w0p = (const int*)d_in[3];
    const int* h1p = (const int*)d_in[4];
    const int* w1p = (const int*)d_in[5];

    // workspace layout (bytes); total ~30.1 MB
    char* ws = (char*)d_ws;
    unsigned short* A3 = (unsigned short*)ws;                  // 14,942,208 B
    unsigned short* B3 = (unsigned short*)(ws + 14942208);     // 14,942,208 B
    float* rs    = (float*)(ws + 29884416);                    // 38,400 B each
    float* cs    = (float*)(ws + 29922816);
    float* rsinv = (float*)(ws + 29961216);
    float* csinv = (float*)(ws + 29999616);
    float* rcm   = (float*)(ws + 30038016);

    float* conf      = (float*)d_out;                          // [N][L][S]: e then conf
    float* out_match = conf + (size_t)Ncst * Lc * Sc;
    float* out_j     = out_match + Ncst * Lc;
    float* out_mconf = out_j + Ncst * Lc;

    init_kernel<<<(Ncst * Lc + 255) / 256, 256, 0, stream>>>(rs, cs);

    convert_kernel<<<(Ncst * LP * (Cc / 8) + 255) / 256, 256, 0, stream>>>(f0, f1, A3, B3);

    dim3 gg(LP / 128, LP / 128, Ncst);   // 38 x 38 x 2
    gemm_kernel<<<gg, 256, 0, stream>>>(A3, B3, conf, rs, cs);

    inv_kernel<<<(Ncst * Lc + 255) / 256, 256, 0, stream>>>(rs, cs, rsinv, csinv);

    conf_kernel<<<Ncst * Lc, 256, 0, stream>>>(conf, rsinv, csinv, rcm);

    finalize_kernel<<<(Ncst * Lc + 255) / 256, 256, 0, stream>>>(
        conf, rcm, h0p, w0p, h1p, w1p, out_match, out_j, out_mconf);
}